// Round 1
// baseline (726.493 us; speedup 1.0000x reference)
//
#include <hip/hip_runtime.h>

// ---------------- problem constants ----------------
#define D_MODEL 1024
#define HID     2752
#define NEXP    8
#define NTOK    4096
#define ALPHA   0.05f

typedef __bf16 bf16_t;
typedef bf16_t bf16x8 __attribute__((ext_vector_type(8)));
typedef float  f32x4  __attribute__((ext_vector_type(4)));

__device__ inline unsigned short f2bf(float f) {
    unsigned int u = __float_as_uint(f);
    u += 0x7fffu + ((u >> 16) & 1u);   // round-to-nearest-even
    return (unsigned short)(u >> 16);
}

__device__ inline bf16x8 ldsFrag(const unsigned short* p) {
    union { uint4 u; bf16x8 b; } t;
    t.u = *(const uint4*)p;
    return t.b;
}

// ---------------- x -> bf16 ----------------
__global__ void tobf16_kernel(const float* __restrict__ x, unsigned short* __restrict__ xbf) {
    int i = (blockIdx.x * 256 + threadIdx.x) * 8;
    float4 a = *(const float4*)(x + i);
    float4 b = *(const float4*)(x + i + 4);
    uint4 o;
    o.x = (unsigned)f2bf(a.x) | ((unsigned)f2bf(a.y) << 16);
    o.y = (unsigned)f2bf(a.z) | ((unsigned)f2bf(a.w) << 16);
    o.z = (unsigned)f2bf(b.x) | ((unsigned)f2bf(b.y) << 16);
    o.w = (unsigned)f2bf(b.z) | ((unsigned)f2bf(b.w) << 16);
    *(uint4*)(xbf + i) = o;
}

// ---------------- router: logits, softmax, top1, stats ----------------
// 1024 threads = 16 waves, 1 token per wave, 16 tokens per block, grid = 256
__global__ void router_kernel(const float* __restrict__ x, const float* __restrict__ Wg,
                              const float* __restrict__ bg,
                              int* __restrict__ eidx, float* __restrict__ gate_p,
                              int* __restrict__ counts, float* __restrict__ ce_sum) {
    __shared__ float ceS[8];
    __shared__ int   cntS[8];
    int tid = threadIdx.x;
    if (tid < 8) { ceS[tid] = 0.f; cntS[tid] = 0; }
    __syncthreads();

    int wid = tid >> 6, lane = tid & 63;
    int t = blockIdx.x * 16 + wid;
    const float* xr = x + (size_t)t * D_MODEL;

    float acc[8];
#pragma unroll
    for (int e = 0; e < 8; ++e) acc[e] = 0.f;

#pragma unroll
    for (int c = 0; c < 4; ++c) {
        int i0 = c * 256 + lane * 4;
        float4 xv = *(const float4*)(xr + i0);
#pragma unroll
        for (int j = 0; j < 4; ++j) {
            const float* wr = Wg + (size_t)(i0 + j) * 8;
            float4 lo = *(const float4*)(wr);
            float4 hi = *(const float4*)(wr + 4);
            float xs = (&xv.x)[j];
            acc[0] += xs * lo.x; acc[1] += xs * lo.y;
            acc[2] += xs * lo.z; acc[3] += xs * lo.w;
            acc[4] += xs * hi.x; acc[5] += xs * hi.y;
            acc[6] += xs * hi.z; acc[7] += xs * hi.w;
        }
    }
#pragma unroll
    for (int e = 0; e < 8; ++e) {
#pragma unroll
        for (int off = 32; off > 0; off >>= 1)
            acc[e] += __shfl_xor(acc[e], off, 64);
    }

    if (lane == 0) {
        float lg[8];
#pragma unroll
        for (int e = 0; e < 8; ++e) lg[e] = acc[e] + bg[e];
        float mx = lg[0]; int am = 0;
#pragma unroll
        for (int e = 1; e < 8; ++e) { if (lg[e] > mx) { mx = lg[e]; am = e; } }
        float ex[8], s = 0.f;
#pragma unroll
        for (int e = 0; e < 8; ++e) { ex[e] = __expf(lg[e] - mx); s += ex[e]; }
        float inv = 1.f / s;
#pragma unroll
        for (int e = 0; e < 8; ++e) atomicAdd(&ceS[e], ex[e] * inv);
        atomicAdd(&cntS[am], 1);
        eidx[t] = am;
        gate_p[t] = ex[am] * inv;
    }
    __syncthreads();
    if (tid < 8) atomicAdd(&ce_sum[tid], ceS[tid]);
    if (tid >= 8 && tid < 16) atomicAdd(&counts[tid - 8], cntS[tid - 8]);
}

// ---------------- offsets + aux loss ----------------
__global__ void offsets_aux_kernel(const int* __restrict__ counts, const float* __restrict__ ce_sum,
                                   int* __restrict__ offs, float* __restrict__ aux_out) {
    if (threadIdx.x == 0) {
        int off = 0; float aux = 0.f;
        for (int e = 0; e < 8; ++e) {
            offs[e] = off; off += counts[e];
            aux += ((float)counts[e] / (float)NTOK) * (ce_sum[e] / (float)NTOK);
        }
        aux_out[0] = ALPHA * (float)NEXP * aux;
    }
}

// ---------------- scatter tokens into per-expert slots ----------------
__global__ void scatter_kernel(const int* __restrict__ eidx, const int* __restrict__ offs,
                               int* __restrict__ fill, int* __restrict__ toks) {
    int t = blockIdx.x * 256 + threadIdx.x;
    int e = eidx[t];
    int pos = atomicAdd(&fill[e], 1);
    toks[offs[e] + pos] = t;
}

// ---------------- GEMM1: h = silu(X Wu) * (X Wv), bf16 out ----------------
// grid (22 n-tiles, 32 m-tiles, 8 experts), 256 threads (4 waves)
__global__ __launch_bounds__(256, 2) void gemm1_kernel(
    const float* __restrict__ Wu, const float* __restrict__ Wv,
    const unsigned short* __restrict__ xbf,
    const int* __restrict__ toks, const int* __restrict__ counts, const int* __restrict__ offs,
    unsigned short* __restrict__ hbuf) {
    const int e = blockIdx.z;
    const int Ne = counts[e];
    const int mt = blockIdx.y;
    if (mt * 128 >= Ne) return;
    const int nt = blockIdx.x;
    const int slot0 = offs[e] + mt * 128;
    const int rowsV = min(128, Ne - mt * 128);
    const int ncol0 = nt * 128;
    const int colsV = min(128, HID - ncol0);

    __shared__ unsigned short As[128 * 64];
    __shared__ unsigned short Bus[128 * 64];
    __shared__ unsigned short Bvs[128 * 64];

    const int tid = threadIdx.x;

    // A staging descriptors: 4 16B chunks per thread
    const unsigned short* aSrc[4];
    int aDst[4];
#pragma unroll
    for (int i = 0; i < 4; ++i) {
        int c = i * 256 + tid;
        int r = c >> 3, ch = c & 7;
        int rr = (r < rowsV) ? r : 0;
        int tok = toks[slot0 + rr];
        aSrc[i] = xbf + (size_t)tok * D_MODEL + ch * 8;
        aDst[i] = r * 64 + ((ch * 8) ^ ((r & 7) << 3));
    }

    // B staging descriptors (transpose to [n][k] in LDS)
    const int bn = tid & 127;
    const int kqb = tid >> 7;
    const int bcol = ncol0 + ((bn < colsV) ? bn : 0);
    const float* buSrc = Wu + (size_t)e * D_MODEL * HID + bcol;
    const float* bvSrc = Wv + (size_t)e * D_MODEL * HID + bcol;

    f32x4 accU[4][4], accV[4][4];
#pragma unroll
    for (int m = 0; m < 4; ++m)
#pragma unroll
        for (int n = 0; n < 4; ++n) {
            accU[m][n] = (f32x4){0.f, 0.f, 0.f, 0.f};
            accV[m][n] = (f32x4){0.f, 0.f, 0.f, 0.f};
        }

    const int lane = tid & 63;
    const int w = tid >> 6;
    const int rbase = (w >> 1) * 64;
    const int cbase = (w & 1) * 64;
    const int lrow = lane & 15;
    const int lkel = (lane >> 4) * 8;

    for (int ks = 0; ks < 16; ++ks) {
        const int k0 = ks * 64;
#pragma unroll
        for (int i = 0; i < 4; ++i) {
            uint4 v = *(const uint4*)(aSrc[i] + k0);
            *(uint4*)(&As[aDst[i]]) = v;
        }
#pragma unroll
        for (int p = 0; p < 8; ++p) {
            int kq = p * 2 + kqb;
            size_t krow = (size_t)(k0 + kq * 4) * HID;
            int dst = bn * 64 + ((kq * 4) ^ ((bn & 7) << 3));
            float f0 = buSrc[krow];
            float f1 = buSrc[krow + HID];
            float f2 = buSrc[krow + 2 * HID];
            float f3 = buSrc[krow + 3 * HID];
            uint2 wd;
            wd.x = (unsigned)f2bf(f0) | ((unsigned)f2bf(f1) << 16);
            wd.y = (unsigned)f2bf(f2) | ((unsigned)f2bf(f3) << 16);
            *(uint2*)(&Bus[dst]) = wd;
            f0 = bvSrc[krow];
            f1 = bvSrc[krow + HID];
            f2 = bvSrc[krow + 2 * HID];
            f3 = bvSrc[krow + 3 * HID];
            wd.x = (unsigned)f2bf(f0) | ((unsigned)f2bf(f1) << 16);
            wd.y = (unsigned)f2bf(f2) | ((unsigned)f2bf(f3) << 16);
            *(uint2*)(&Bvs[dst]) = wd;
        }
        __syncthreads();

#pragma unroll
        for (int kk = 0; kk < 2; ++kk) {
            const int kel = kk * 32 + lkel;
            bf16x8 af[4], bu[4], bv[4];
#pragma unroll
            for (int m = 0; m < 4; ++m) {
                int r = rbase + m * 16 + lrow;
                af[m] = ldsFrag(&As[r * 64 + (kel ^ ((r & 7) << 3))]);
            }
#pragma unroll
            for (int n = 0; n < 4; ++n) {
                int rn = cbase + n * 16 + lrow;
                int off = rn * 64 + (kel ^ ((rn & 7) << 3));
                bu[n] = ldsFrag(&Bus[off]);
                bv[n] = ldsFrag(&Bvs[off]);
            }
#pragma unroll
            for (int m = 0; m < 4; ++m)
#pragma unroll
                for (int n = 0; n < 4; ++n) {
                    accU[m][n] = __builtin_amdgcn_mfma_f32_16x16x32_bf16(af[m], bu[n], accU[m][n], 0, 0, 0);
                    accV[m][n] = __builtin_amdgcn_mfma_f32_16x16x32_bf16(af[m], bv[n], accV[m][n], 0, 0, 0);
                }
        }
        __syncthreads();
    }

    // epilogue: h = silu(u) * v (bf16)
#pragma unroll
    for (int m = 0; m < 4; ++m) {
#pragma unroll
        for (int i = 0; i < 4; ++i) {
            int r = rbase + m * 16 + (lane >> 4) * 4 + i;
            if (r >= rowsV) continue;
            size_t rowOff = (size_t)(slot0 + r) * HID + ncol0;
#pragma unroll
            for (int n = 0; n < 4; ++n) {
                int c = cbase + n * 16 + (lane & 15);
                if (c < colsV) {
                    float u = accU[m][n][i];
                    float v = accV[m][n][i];
                    float s = u / (1.f + __expf(-u));
                    hbuf[rowOff + c] = f2bf(s * v);
                }
            }
        }
    }
}

// ---------------- GEMM2: y[tok] = p * (h Wd) ----------------
// grid (8 n-tiles, 32 m-tiles, 8 experts), 256 threads
__global__ __launch_bounds__(256, 2) void gemm2_kernel(
    const float* __restrict__ Wd, const unsigned short* __restrict__ hbuf,
    const int* __restrict__ toks, const int* __restrict__ counts, const int* __restrict__ offs,
    const float* __restrict__ gate_p, float* __restrict__ yout) {
    const int e = blockIdx.z;
    const int Ne = counts[e];
    const int mt = blockIdx.y;
    if (mt * 128 >= Ne) return;
    const int nt = blockIdx.x;
    const int slot0 = offs[e] + mt * 128;
    const int rowsV = min(128, Ne - mt * 128);
    const int ncol0 = nt * 128;

    __shared__ unsigned short As[128 * 64];
    __shared__ unsigned short Bs[128 * 64];

    const int tid = threadIdx.x;

    const unsigned short* aSrc[4];
    int aDst[4];
#pragma unroll
    for (int i = 0; i < 4; ++i) {
        int c = i * 256 + tid;
        int r = c >> 3, ch = c & 7;
        int rr = (r < rowsV) ? r : 0;
        aSrc[i] = hbuf + (size_t)(slot0 + rr) * HID + ch * 8;
        aDst[i] = r * 64 + ((ch * 8) ^ ((r & 7) << 3));
    }

    const int bn = tid & 127;
    const int kqb = tid >> 7;
    const float* bSrc = Wd + (size_t)e * HID * D_MODEL + (ncol0 + bn);

    f32x4 acc[4][4];
#pragma unroll
    for (int m = 0; m < 4; ++m)
#pragma unroll
        for (int n = 0; n < 4; ++n) acc[m][n] = (f32x4){0.f, 0.f, 0.f, 0.f};

    const int lane = tid & 63;
    const int w = tid >> 6;
    const int rbase = (w >> 1) * 64;
    const int cbase = (w & 1) * 64;
    const int lrow = lane & 15;
    const int lkel = (lane >> 4) * 8;

    for (int ks = 0; ks < 43; ++ks) {
        const int k0 = ks * 64;
#pragma unroll
        for (int i = 0; i < 4; ++i) {
            uint4 v = *(const uint4*)(aSrc[i] + k0);
            *(uint4*)(&As[aDst[i]]) = v;
        }
#pragma unroll
        for (int p = 0; p < 8; ++p) {
            int kq = p * 2 + kqb;
            size_t krow = (size_t)(k0 + kq * 4) * D_MODEL;
            int dst = bn * 64 + ((kq * 4) ^ ((bn & 7) << 3));
            float f0 = bSrc[krow];
            float f1 = bSrc[krow + D_MODEL];
            float f2 = bSrc[krow + 2 * D_MODEL];
            float f3 = bSrc[krow + 3 * D_MODEL];
            uint2 wd;
            wd.x = (unsigned)f2bf(f0) | ((unsigned)f2bf(f1) << 16);
            wd.y = (unsigned)f2bf(f2) | ((unsigned)f2bf(f3) << 16);
            *(uint2*)(&Bs[dst]) = wd;
        }
        __syncthreads();

#pragma unroll
        for (int kk = 0; kk < 2; ++kk) {
            const int kel = kk * 32 + lkel;
            bf16x8 af[4], bf[4];
#pragma unroll
            for (int m = 0; m < 4; ++m) {
                int r = rbase + m * 16 + lrow;
                af[m] = ldsFrag(&As[r * 64 + (kel ^ ((r & 7) << 3))]);
            }
#pragma unroll
            for (int n = 0; n < 4; ++n) {
                int rn = cbase + n * 16 + lrow;
                bf[n] = ldsFrag(&Bs[rn * 64 + (kel ^ ((rn & 7) << 3))]);
            }
#pragma unroll
            for (int m = 0; m < 4; ++m)
#pragma unroll
                for (int n = 0; n < 4; ++n)
                    acc[m][n] = __builtin_amdgcn_mfma_f32_16x16x32_bf16(af[m], bf[n], acc[m][n], 0, 0, 0);
        }
        __syncthreads();
    }

#pragma unroll
    for (int m = 0; m < 4; ++m) {
#pragma unroll
        for (int i = 0; i < 4; ++i) {
            int r = rbase + m * 16 + (lane >> 4) * 4 + i;
            if (r >= rowsV) continue;
            int tok = toks[slot0 + r];
            float p = gate_p[tok];
            float* yrow = yout + (size_t)tok * D_MODEL + ncol0;
#pragma unroll
            for (int n = 0; n < 4; ++n) {
                int c = cbase + n * 16 + (lane & 15);
                yrow[c] = p * acc[m][n][i];
            }
        }
    }
}

// ---------------- launch ----------------
extern "C" void kernel_launch(void* const* d_in, const int* in_sizes, int n_in,
                              void* d_out, int out_size, void* d_ws, size_t ws_size,
                              hipStream_t stream) {
    const float* x  = (const float*)d_in[0];
    const float* Wg = (const float*)d_in[1];
    const float* bg = (const float*)d_in[2];
    const float* Wu = (const float*)d_in[3];
    const float* Wv = (const float*)d_in[4];
    const float* Wd = (const float*)d_in[5];
    float* yout = (float*)d_out;
    float* aux_out = yout + (size_t)NTOK * D_MODEL;

    char* ws = (char*)d_ws;
    int*   counts = (int*)(ws + 0);
    int*   offs   = (int*)(ws + 32);
    float* ce_sum = (float*)(ws + 64);
    int*   fill   = (int*)(ws + 96);
    int*   eidx   = (int*)(ws + 128);                 // 4096 ints
    float* gate_p = (float*)(ws + 16512);             // 4096 floats
    int*   toks   = (int*)(ws + 32896);               // 4096 ints
    unsigned short* xbf  = (unsigned short*)(ws + 49280);    // 8 MB
    unsigned short* hbuf = (unsigned short*)(ws + 8437888);  // 22.5 MB

    hipMemsetAsync(ws, 0, 128, stream);
    tobf16_kernel<<<2048, 256, 0, stream>>>(x, xbf);
    router_kernel<<<256, 1024, 0, stream>>>(x, Wg, bg, eidx, gate_p, counts, ce_sum);
    offsets_aux_kernel<<<1, 64, 0, stream>>>(counts, ce_sum, offs, aux_out);
    scatter_kernel<<<16, 256, 0, stream>>>(eidx, offs, fill, toks);
    gemm1_kernel<<<dim3(22, 32, 8), 256, 0, stream>>>(Wu, Wv, xbf, toks, counts, offs, hbuf);
    gemm2_kernel<<<dim3(8, 32, 8), 256, 0, stream>>>(Wd, hbuf, toks, counts, offs, gate_p, yout);
}

// Round 2
// 283.460 us; speedup vs baseline: 2.5629x; 2.5629x over previous
//
#include <hip/hip_runtime.h>

// ---------------- problem constants ----------------
#define D_MODEL 1024
#define HID     2752
#define NEXP    8
#define NTOK    4096
#define ALPHA   0.05f

typedef __bf16 bf16_t;
typedef bf16_t bf16x8 __attribute__((ext_vector_type(8)));
typedef float  f32x4  __attribute__((ext_vector_type(4)));

__device__ inline unsigned short f2bf(float f) {
    unsigned int u = __float_as_uint(f);
    u += 0x7fffu + ((u >> 16) & 1u);   // round-to-nearest-even
    return (unsigned short)(u >> 16);
}

__device__ inline bf16x8 ldsFrag(const unsigned short* p) {
    union { uint4 u; bf16x8 b; } t;
    t.u = *(const uint4*)p;
    return t.b;
}

__device__ inline void gload_lds16(const void* g, void* l) {
    __builtin_amdgcn_global_load_lds((const __attribute__((address_space(1))) void*)g,
                                     (__attribute__((address_space(3))) void*)l, 16, 0, 0);
}

// ---------------- x -> bf16 ----------------
__global__ void tobf16_kernel(const float* __restrict__ x, unsigned short* __restrict__ xbf) {
    int i = (blockIdx.x * 256 + threadIdx.x) * 8;
    float4 a = *(const float4*)(x + i);
    float4 b = *(const float4*)(x + i + 4);
    uint4 o;
    o.x = (unsigned)f2bf(a.x) | ((unsigned)f2bf(a.y) << 16);
    o.y = (unsigned)f2bf(a.z) | ((unsigned)f2bf(a.w) << 16);
    o.z = (unsigned)f2bf(b.x) | ((unsigned)f2bf(b.y) << 16);
    o.w = (unsigned)f2bf(b.z) | ((unsigned)f2bf(b.w) << 16);
    *(uint4*)(xbf + i) = o;
}

// ---------------- weight transpose+convert: [R][C] f32 -> [C][R] bf16 ----------------
// 64x64 tiles, 256 threads. LDS f32 [64][65]: conflict-free scalar r/w,
// coalesced 256B input segments, 128B output segments.
__global__ __launch_bounds__(256) void transpose_kernel(const float* __restrict__ in,
                                                        unsigned short* __restrict__ out,
                                                        int R, int C) {
    __shared__ float tile[64 * 65];
    const int e = blockIdx.z;
    const float* src = in + (size_t)e * R * C;
    unsigned short* dst = out + (size_t)e * R * C;
    const int c0 = blockIdx.x * 64, r0 = blockIdx.y * 64;
    const int tid = threadIdx.x;
#pragma unroll
    for (int j = 0; j < 4; ++j) {
        int f = j * 256 + tid;
        int row = f >> 4, c4 = f & 15;
        float4 v = *(const float4*)(src + (size_t)(r0 + row) * C + c0 + c4 * 4);
        float* t = &tile[row * 65 + c4 * 4];
        t[0] = v.x; t[1] = v.y; t[2] = v.z; t[3] = v.w;
    }
    __syncthreads();
#pragma unroll
    for (int j = 0; j < 2; ++j) {
        int f = j * 256 + tid;
        int orow = f >> 3, kc = f & 7;
        unsigned short pk[8];
#pragma unroll
        for (int q = 0; q < 8; ++q) pk[q] = f2bf(tile[(kc * 8 + q) * 65 + orow]);
        *(uint4*)(dst + (size_t)(c0 + orow) * R + r0 + kc * 8) = *(uint4*)pk;
    }
}

// ---------------- router ----------------
__global__ void router_kernel(const float* __restrict__ x, const float* __restrict__ Wg,
                              const float* __restrict__ bg,
                              int* __restrict__ eidx, float* __restrict__ gate_p,
                              int* __restrict__ counts, float* __restrict__ ce_sum) {
    __shared__ float ceS[8];
    __shared__ int   cntS[8];
    int tid = threadIdx.x;
    if (tid < 8) { ceS[tid] = 0.f; cntS[tid] = 0; }
    __syncthreads();

    int wid = tid >> 6, lane = tid & 63;
    int t = blockIdx.x * 16 + wid;
    const float* xr = x + (size_t)t * D_MODEL;

    float acc[8];
#pragma unroll
    for (int e = 0; e < 8; ++e) acc[e] = 0.f;

#pragma unroll
    for (int c = 0; c < 4; ++c) {
        int i0 = c * 256 + lane * 4;
        float4 xv = *(const float4*)(xr + i0);
#pragma unroll
        for (int j = 0; j < 4; ++j) {
            const float* wr = Wg + (size_t)(i0 + j) * 8;
            float4 lo = *(const float4*)(wr);
            float4 hi = *(const float4*)(wr + 4);
            float xs = (&xv.x)[j];
            acc[0] += xs * lo.x; acc[1] += xs * lo.y;
            acc[2] += xs * lo.z; acc[3] += xs * lo.w;
            acc[4] += xs * hi.x; acc[5] += xs * hi.y;
            acc[6] += xs * hi.z; acc[7] += xs * hi.w;
        }
    }
#pragma unroll
    for (int e = 0; e < 8; ++e) {
#pragma unroll
        for (int off = 32; off > 0; off >>= 1)
            acc[e] += __shfl_xor(acc[e], off, 64);
    }

    if (lane == 0) {
        float lg[8];
#pragma unroll
        for (int e = 0; e < 8; ++e) lg[e] = acc[e] + bg[e];
        float mx = lg[0]; int am = 0;
#pragma unroll
        for (int e = 1; e < 8; ++e) { if (lg[e] > mx) { mx = lg[e]; am = e; } }
        float ex[8], s = 0.f;
#pragma unroll
        for (int e = 0; e < 8; ++e) { ex[e] = __expf(lg[e] - mx); s += ex[e]; }
        float inv = 1.f / s;
#pragma unroll
        for (int e = 0; e < 8; ++e) atomicAdd(&ceS[e], ex[e] * inv);
        atomicAdd(&cntS[am], 1);
        eidx[t] = am;
        gate_p[t] = ex[am] * inv;
    }
    __syncthreads();
    if (tid < 8) atomicAdd(&ce_sum[tid], ceS[tid]);
    if (tid >= 8 && tid < 16) atomicAdd(&counts[tid - 8], cntS[tid - 8]);
}

// ---------------- offsets + aux loss ----------------
__global__ void offsets_aux_kernel(const int* __restrict__ counts, const float* __restrict__ ce_sum,
                                   int* __restrict__ offs, float* __restrict__ aux_out) {
    if (threadIdx.x == 0) {
        int off = 0; float aux = 0.f;
        for (int e = 0; e < 8; ++e) {
            offs[e] = off; off += counts[e];
            aux += ((float)counts[e] / (float)NTOK) * (ce_sum[e] / (float)NTOK);
        }
        aux_out[0] = ALPHA * (float)NEXP * aux;
    }
}

// ---------------- scatter ----------------
__global__ void scatter_kernel(const int* __restrict__ eidx, const int* __restrict__ offs,
                               int* __restrict__ fill, int* __restrict__ toks) {
    int t = blockIdx.x * 256 + threadIdx.x;
    int e = eidx[t];
    int pos = atomicAdd(&fill[e], 1);
    toks[offs[e] + pos] = t;
}

// ---------------- GEMM1: h = silu(X WuT^T) * (X WvT^T), bf16 out ----------------
// 128x128 tile, BK=64, 4 waves, global_load_lds staging with source-side XOR swizzle.
__global__ __launch_bounds__(256, 2) void gemm1_kernel(
    const unsigned short* __restrict__ WuT, const unsigned short* __restrict__ WvT,
    const unsigned short* __restrict__ xbf,
    const int* __restrict__ toks, const int* __restrict__ counts, const int* __restrict__ offs,
    unsigned short* __restrict__ hbuf) {
    const int e = blockIdx.z;
    const int Ne = counts[e];
    const int mt = blockIdx.y;
    if (mt * 128 >= Ne) return;
    const int nt = blockIdx.x;
    const int slot0 = offs[e] + mt * 128;
    const int rowsV = min(128, Ne - mt * 128);
    const int ncol0 = nt * 128;
    const int colsV = min(128, HID - ncol0);

    __shared__ unsigned short As[128 * 64];
    __shared__ unsigned short Bus[128 * 64];
    __shared__ unsigned short Bvs[128 * 64];

    const int tid = threadIdx.x;

    // staging descriptors: flat chunk c = i*256+tid; LDS row r=c>>3, slot ch=c&7.
    // source chunk = ch ^ (r&7)  ->  linear LDS holds swizzled layout (rule #21).
    const unsigned short* aS[4];
    const unsigned short* buS[4];
    const unsigned short* bvS[4];
    unsigned short* aD[4];
    unsigned short* buD[4];
    unsigned short* bvD[4];
#pragma unroll
    for (int i = 0; i < 4; ++i) {
        int c = i * 256 + tid;
        int r = c >> 3, ch = c & 7;
        int srcOff = ((ch ^ (r & 7)) * 8);
        int ar = min(r, rowsV - 1);
        int tok = toks[slot0 + ar];
        aS[i] = xbf + (size_t)tok * D_MODEL + srcOff;
        int bn = ncol0 + min(r, colsV - 1);
        buS[i] = WuT + ((size_t)e * HID + bn) * D_MODEL + srcOff;
        bvS[i] = WvT + ((size_t)e * HID + bn) * D_MODEL + srcOff;
        aD[i]  = As  + c * 8;
        buD[i] = Bus + c * 8;
        bvD[i] = Bvs + c * 8;
    }

    f32x4 accU[4][4], accV[4][4];
#pragma unroll
    for (int m = 0; m < 4; ++m)
#pragma unroll
        for (int n = 0; n < 4; ++n) {
            accU[m][n] = (f32x4){0.f, 0.f, 0.f, 0.f};
            accV[m][n] = (f32x4){0.f, 0.f, 0.f, 0.f};
        }

    const int lane = tid & 63;
    const int w = tid >> 6;
    const int rbase = (w >> 1) * 64;
    const int cbase = (w & 1) * 64;
    const int lrow = lane & 15;
    const int lchunk = lane >> 4;   // k-chunk within 32-el group

    for (int ks = 0; ks < 16; ++ks) {
#pragma unroll
        for (int i = 0; i < 4; ++i) gload_lds16(aS[i],  aD[i]);
#pragma unroll
        for (int i = 0; i < 4; ++i) gload_lds16(buS[i], buD[i]);
#pragma unroll
        for (int i = 0; i < 4; ++i) gload_lds16(bvS[i], bvD[i]);
#pragma unroll
        for (int i = 0; i < 4; ++i) { aS[i] += 64; buS[i] += 64; bvS[i] += 64; }
        __syncthreads();

#pragma unroll
        for (int kk = 0; kk < 2; ++kk) {
            const int g = kk * 4 + lchunk;   // global k-chunk 0..7
            bf16x8 af[4], bu[4], bv[4];
#pragma unroll
            for (int m = 0; m < 4; ++m) {
                int r = rbase + m * 16 + lrow;
                af[m] = ldsFrag(&As[r * 64 + ((g ^ (r & 7)) * 8)]);
            }
#pragma unroll
            for (int n = 0; n < 4; ++n) {
                int rn = cbase + n * 16 + lrow;
                int off = rn * 64 + ((g ^ (rn & 7)) * 8);
                bu[n] = ldsFrag(&Bus[off]);
                bv[n] = ldsFrag(&Bvs[off]);
            }
#pragma unroll
            for (int m = 0; m < 4; ++m)
#pragma unroll
                for (int n = 0; n < 4; ++n) {
                    accU[m][n] = __builtin_amdgcn_mfma_f32_16x16x32_bf16(af[m], bu[n], accU[m][n], 0, 0, 0);
                    accV[m][n] = __builtin_amdgcn_mfma_f32_16x16x32_bf16(af[m], bv[n], accV[m][n], 0, 0, 0);
                }
        }
        __syncthreads();
    }

    // epilogue: h = silu(u) * v (bf16)
#pragma unroll
    for (int m = 0; m < 4; ++m) {
#pragma unroll
        for (int i = 0; i < 4; ++i) {
            int r = rbase + m * 16 + (lane >> 4) * 4 + i;
            if (r >= rowsV) continue;
            size_t rowOff = (size_t)(slot0 + r) * HID + ncol0;
#pragma unroll
            for (int n = 0; n < 4; ++n) {
                int c = cbase + n * 16 + (lane & 15);
                if (c < colsV) {
                    float u = accU[m][n][i];
                    float v = accV[m][n][i];
                    float s = u / (1.f + __expf(-u));
                    hbuf[rowOff + c] = f2bf(s * v);
                }
            }
        }
    }
}

// ---------------- GEMM2: y[tok] = p * (h WdT^T) ----------------
__global__ __launch_bounds__(256, 3) void gemm2_kernel(
    const unsigned short* __restrict__ WdT, const unsigned short* __restrict__ hbuf,
    const int* __restrict__ toks, const int* __restrict__ counts, const int* __restrict__ offs,
    const float* __restrict__ gate_p, float* __restrict__ yout) {
    const int e = blockIdx.z;
    const int Ne = counts[e];
    const int mt = blockIdx.y;
    if (mt * 128 >= Ne) return;
    const int nt = blockIdx.x;
    const int slot0 = offs[e] + mt * 128;
    const int rowsV = min(128, Ne - mt * 128);
    const int ncol0 = nt * 128;

    __shared__ unsigned short As[128 * 64];
    __shared__ unsigned short Bs[128 * 64];

    const int tid = threadIdx.x;

    const unsigned short* aS[4];
    const unsigned short* bS[4];
    unsigned short* aD[4];
    unsigned short* bD[4];
#pragma unroll
    for (int i = 0; i < 4; ++i) {
        int c = i * 256 + tid;
        int r = c >> 3, ch = c & 7;
        int srcOff = ((ch ^ (r & 7)) * 8);
        int ar = min(r, rowsV - 1);
        aS[i] = hbuf + (size_t)(slot0 + ar) * HID + srcOff;
        bS[i] = WdT + ((size_t)e * D_MODEL + ncol0 + r) * HID + srcOff;
        aD[i] = As + c * 8;
        bD[i] = Bs + c * 8;
    }

    f32x4 acc[4][4];
#pragma unroll
    for (int m = 0; m < 4; ++m)
#pragma unroll
        for (int n = 0; n < 4; ++n) acc[m][n] = (f32x4){0.f, 0.f, 0.f, 0.f};

    const int lane = tid & 63;
    const int w = tid >> 6;
    const int rbase = (w >> 1) * 64;
    const int cbase = (w & 1) * 64;
    const int lrow = lane & 15;
    const int lchunk = lane >> 4;

    for (int ks = 0; ks < 43; ++ks) {
#pragma unroll
        for (int i = 0; i < 4; ++i) gload_lds16(aS[i], aD[i]);
#pragma unroll
        for (int i = 0; i < 4; ++i) gload_lds16(bS[i], bD[i]);
#pragma unroll
        for (int i = 0; i < 4; ++i) { aS[i] += 64; bS[i] += 64; }
        __syncthreads();

#pragma unroll
        for (int kk = 0; kk < 2; ++kk) {
            const int g = kk * 4 + lchunk;
            bf16x8 af[4], bf[4];
#pragma unroll
            for (int m = 0; m < 4; ++m) {
                int r = rbase + m * 16 + lrow;
                af[m] = ldsFrag(&As[r * 64 + ((g ^ (r & 7)) * 8)]);
            }
#pragma unroll
            for (int n = 0; n < 4; ++n) {
                int rn = cbase + n * 16 + lrow;
                bf[n] = ldsFrag(&Bs[rn * 64 + ((g ^ (rn & 7)) * 8)]);
            }
#pragma unroll
            for (int m = 0; m < 4; ++m)
#pragma unroll
                for (int n = 0; n < 4; ++n)
                    acc[m][n] = __builtin_amdgcn_mfma_f32_16x16x32_bf16(af[m], bf[n], acc[m][n], 0, 0, 0);
        }
        __syncthreads();
    }

#pragma unroll
    for (int m = 0; m < 4; ++m) {
#pragma unroll
        for (int i = 0; i < 4; ++i) {
            int r = rbase + m * 16 + (lane >> 4) * 4 + i;
            if (r >= rowsV) continue;
            int tok = toks[slot0 + r];
            float p = gate_p[tok];
            float* yrow = yout + (size_t)tok * D_MODEL + ncol0;
#pragma unroll
            for (int n = 0; n < 4; ++n) {
                int c = cbase + n * 16 + (lane & 15);
                yrow[c] = p * acc[m][n][i];
            }
        }
    }
}

// ---------------- launch ----------------
extern "C" void kernel_launch(void* const* d_in, const int* in_sizes, int n_in,
                              void* d_out, int out_size, void* d_ws, size_t ws_size,
                              hipStream_t stream) {
    const float* x  = (const float*)d_in[0];
    const float* Wg = (const float*)d_in[1];
    const float* bg = (const float*)d_in[2];
    const float* Wu = (const float*)d_in[3];
    const float* Wv = (const float*)d_in[4];
    const float* Wd = (const float*)d_in[5];
    float* yout = (float*)d_out;
    float* aux_out = yout + (size_t)NTOK * D_MODEL;

    char* ws = (char*)d_ws;
    int*   counts = (int*)(ws + 0);
    int*   offs   = (int*)(ws + 32);
    float* ce_sum = (float*)(ws + 64);
    int*   fill   = (int*)(ws + 96);
    int*   eidx   = (int*)(ws + 128);
    float* gate_p = (float*)(ws + 16512);
    int*   toks   = (int*)(ws + 32896);
    unsigned short* xbf  = (unsigned short*)(ws + 65536);      // 8 MB
    unsigned short* hbuf = (unsigned short*)(ws + 8454144);    // 22.5 MB
    unsigned short* WuT  = (unsigned short*)(ws + 30998528);   // 45 MB
    unsigned short* WvT  = (unsigned short*)(ws + 76087296);   // 45 MB
    unsigned short* WdT  = WuT;                                // reused after gemm1

    hipMemsetAsync(ws, 0, 128, stream);
    tobf16_kernel<<<2048, 256, 0, stream>>>(x, xbf);
    router_kernel<<<256, 1024, 0, stream>>>(x, Wg, bg, eidx, gate_p, counts, ce_sum);
    offsets_aux_kernel<<<1, 64, 0, stream>>>(counts, ce_sum, offs, aux_out);
    scatter_kernel<<<16, 256, 0, stream>>>(eidx, offs, fill, toks);
    transpose_kernel<<<dim3(HID / 64, D_MODEL / 64, 8), 256, 0, stream>>>(Wu, WuT, D_MODEL, HID);
    transpose_kernel<<<dim3(HID / 64, D_MODEL / 64, 8), 256, 0, stream>>>(Wv, WvT, D_MODEL, HID);
    gemm1_kernel<<<dim3(22, 32, 8), 256, 0, stream>>>(WuT, WvT, xbf, toks, counts, offs, hbuf);
    transpose_kernel<<<dim3(D_MODEL / 64, HID / 64, 8), 256, 0, stream>>>(Wd, WdT, HID, D_MODEL);
    gemm2_kernel<<<dim3(8, 32, 8), 256, 0, stream>>>(WdT, hbuf, toks, counts, offs, gate_p, yout);
}